// Round 1
// baseline (83.280 us; speedup 1.0000x reference)
//
#include <hip/hip_runtime.h>

// Problem constants (from reference setup)
constexpr int B   = 1024;
constexpr int S   = 16;
constexpr int DEG = 32;
constexpr int D   = 256;
constexpr int G   = B * S;          // 16384 groups
constexpr int D3  = 3 * D;          // 768

// One 64-lane wave per group. Lane l owns float4 columns [4l, 4l+4).
// 4 waves (4 groups) per 256-thread block.
__global__ __launch_bounds__(256) void mean_agg_kernel(
    const int*   __restrict__ nbr_ids,    // [N] = [G*DEG]
    const int*   __restrict__ batch_idx,  // [G]
    const int*   __restrict__ pos_idx,    // [G]
    const int*   __restrict__ s_tem,      // [B]
    const int*   __restrict__ r_tem,      // [B]
    const float* __restrict__ dt_flat,    // [G]
    const float* __restrict__ ent,        // [NUM_ENTS, D]
    const float* __restrict__ rel,        // [NUM_RELS, D]
    float*       __restrict__ out)        // [B*S*3D] followed by [B*S]
{
    const int wave = threadIdx.x >> 6;          // 0..3
    const int lane = threadIdx.x & 63;          // 0..63
    const int g    = (blockIdx.x << 2) + wave;  // group id
    if (g >= G) return;

    const int b = batch_idx[g];
    const int p = pos_idx[g];

    // ---- segment mean over DEG=32 neighbor rows ----
    const int* ids = nbr_ids + g * DEG;
    float4 acc = make_float4(0.f, 0.f, 0.f, 0.f);
    #pragma unroll
    for (int k = 0; k < DEG; ++k) {
        const int e = ids[k];   // wave-uniform load (broadcast)
        const float4 v = reinterpret_cast<const float4*>(ent + (size_t)e * D)[lane];
        acc.x += v.x; acc.y += v.y; acc.z += v.z; acc.w += v.w;
    }
    const float inv = 1.0f / (float)DEG;
    acc.x *= inv; acc.y *= inv; acc.z *= inv; acc.w *= inv;

    float* orow = out + ((size_t)b * S + p) * D3;
    reinterpret_cast<float4*>(orow)[lane] = acc;

    // ---- subject entity embed ----
    const int se = s_tem[b];
    const float4 sv = reinterpret_cast<const float4*>(ent + (size_t)se * D)[lane];
    reinterpret_cast<float4*>(orow + D)[lane] = sv;

    // ---- relation embed ----
    const int re = r_tem[b];
    const float4 rv = reinterpret_cast<const float4*>(rel + (size_t)re * D)[lane];
    reinterpret_cast<float4*>(orow + 2 * D)[lane] = rv;

    // ---- dt scatter ----
    if (lane == 0) {
        out[(size_t)B * S * D3 + (size_t)b * S + p] = dt_flat[g];
    }
}

extern "C" void kernel_launch(void* const* d_in, const int* in_sizes, int n_in,
                              void* d_out, int out_size, void* d_ws, size_t ws_size,
                              hipStream_t stream) {
    const int*   nbr_ids   = (const int*)  d_in[0];
    // d_in[1] = seg_ids: implied by g*DEG layout (sorted, DEG per group) — unused
    const int*   batch_idx = (const int*)  d_in[2];
    const int*   pos_idx   = (const int*)  d_in[3];
    const int*   s_tem     = (const int*)  d_in[4];
    const int*   r_tem     = (const int*)  d_in[5];
    const float* dt_flat   = (const float*)d_in[6];
    const float* ent       = (const float*)d_in[7];
    const float* rel       = (const float*)d_in[8];
    float*       out       = (float*)d_out;

    const int blocks = G / 4;  // 4 groups (waves) per 256-thread block
    mean_agg_kernel<<<blocks, 256, 0, stream>>>(
        nbr_ids, batch_idx, pos_idx, s_tem, r_tem, dt_flat, ent, rel, out);
}

// Round 2
// 82.121 us; speedup vs baseline: 1.0141x; 1.0141x over previous
//
#include <hip/hip_runtime.h>

// Problem constants (from reference setup)
constexpr int B   = 1024;
constexpr int S   = 16;
constexpr int DEG = 32;
constexpr int D   = 256;
constexpr int G   = B * S;          // 16384 groups
constexpr int D3  = 3 * D;          // 768

typedef float f32x4 __attribute__((ext_vector_type(4)));

// One 64-lane wave per group. Lane l owns float4 columns [4l, 4l+4).
// 4 waves (4 groups) per 256-thread block.
__global__ __launch_bounds__(256) void mean_agg_kernel(
    const int*   __restrict__ nbr_ids,    // [N] = [G*DEG]
    const int*   __restrict__ batch_idx,  // [G]
    const int*   __restrict__ pos_idx,    // [G]
    const int*   __restrict__ s_tem,      // [B]
    const int*   __restrict__ r_tem,      // [B]
    const float* __restrict__ dt_flat,    // [G]
    const float* __restrict__ ent,        // [NUM_ENTS, D]
    const float* __restrict__ rel,        // [NUM_RELS, D]
    float*       __restrict__ out)        // [B*S*3D] followed by [B*S]
{
    const int wave = threadIdx.x >> 6;          // 0..3
    const int lane = threadIdx.x & 63;          // 0..63
    // Wave-uniform group id, forced into an SGPR so neighbor-id loads become
    // scalar (s_load) and row loads take the saddr form (1 shared voffset).
    const int g = __builtin_amdgcn_readfirstlane((blockIdx.x << 2) + wave);

    const int b = batch_idx[g];
    const int p = pos_idx[g];

    // ---- segment mean over DEG=32 neighbor rows ----
    const int* ids = nbr_ids + g * DEG;   // SGPR base, const offsets -> s_load
    f32x4 acc0 = {0.f, 0.f, 0.f, 0.f};
    f32x4 acc1 = {0.f, 0.f, 0.f, 0.f};

    #pragma unroll
    for (int k0 = 0; k0 < DEG; k0 += 8) {
        f32x4 v0 = reinterpret_cast<const f32x4*>(ent + (size_t)ids[k0 + 0] * D)[lane];
        f32x4 v1 = reinterpret_cast<const f32x4*>(ent + (size_t)ids[k0 + 1] * D)[lane];
        f32x4 v2 = reinterpret_cast<const f32x4*>(ent + (size_t)ids[k0 + 2] * D)[lane];
        f32x4 v3 = reinterpret_cast<const f32x4*>(ent + (size_t)ids[k0 + 3] * D)[lane];
        f32x4 v4 = reinterpret_cast<const f32x4*>(ent + (size_t)ids[k0 + 4] * D)[lane];
        f32x4 v5 = reinterpret_cast<const f32x4*>(ent + (size_t)ids[k0 + 5] * D)[lane];
        f32x4 v6 = reinterpret_cast<const f32x4*>(ent + (size_t)ids[k0 + 6] * D)[lane];
        f32x4 v7 = reinterpret_cast<const f32x4*>(ent + (size_t)ids[k0 + 7] * D)[lane];
        acc0 += v0; acc1 += v1;
        acc0 += v2; acc1 += v3;
        acc0 += v4; acc1 += v5;
        acc0 += v6; acc1 += v7;
    }
    f32x4 acc = (acc0 + acc1) * (1.0f / (float)DEG);

    float* orow = out + ((size_t)b * S + p) * D3;
    __builtin_nontemporal_store(acc, reinterpret_cast<f32x4*>(orow) + lane);

    // ---- subject entity embed ----
    const int se = s_tem[b];
    f32x4 sv = reinterpret_cast<const f32x4*>(ent + (size_t)se * D)[lane];
    __builtin_nontemporal_store(sv, reinterpret_cast<f32x4*>(orow + D) + lane);

    // ---- relation embed ----
    const int re = r_tem[b];
    f32x4 rv = reinterpret_cast<const f32x4*>(rel + (size_t)re * D)[lane];
    __builtin_nontemporal_store(rv, reinterpret_cast<f32x4*>(orow + 2 * D) + lane);

    // ---- dt scatter ----
    if (lane == 0) {
        __builtin_nontemporal_store(dt_flat[g],
            out + (size_t)B * S * D3 + (size_t)b * S + p);
    }
}

extern "C" void kernel_launch(void* const* d_in, const int* in_sizes, int n_in,
                              void* d_out, int out_size, void* d_ws, size_t ws_size,
                              hipStream_t stream) {
    const int*   nbr_ids   = (const int*)  d_in[0];
    // d_in[1] = seg_ids: implied by g*DEG layout (sorted, DEG per group) — unused
    const int*   batch_idx = (const int*)  d_in[2];
    const int*   pos_idx   = (const int*)  d_in[3];
    const int*   s_tem     = (const int*)  d_in[4];
    const int*   r_tem     = (const int*)  d_in[5];
    const float* dt_flat   = (const float*)d_in[6];
    const float* ent       = (const float*)d_in[7];
    const float* rel       = (const float*)d_in[8];
    float*       out       = (float*)d_out;

    const int blocks = G / 4;  // 4 groups (waves) per 256-thread block
    mean_agg_kernel<<<blocks, 256, 0, stream>>>(
        nbr_ids, batch_idx, pos_idx, s_tem, r_tem, dt_flat, ent, rel, out);
}